// Round 8
// baseline (73.488 us; speedup 1.0000x reference)
//
#include <hip/hip_runtime.h>
#include <math.h>

#define B_ 32
#define M_ 64
#define N_ 5000
#define L_ 100
#define H_ 8
#define D_ 16
#define E_ 128
#define NI4 1250   // N_/4
#define T0 0.032f  // prefilter threshold: uniform[0,1) -> ~160 candidates
#define CAP 256    // candidate buffer

// per-row state layout inside OUT (row base + offset, floats):
//   [0..99] sdn  [128..227] st  [256..355] sm  [384..483] idx(u32 bits)  [512..611] s2
#define ST_SD  0
#define ST_TH  128
#define ST_SM  256
#define ST_IX  384
#define ST_S2  512

// ---- workspace float offsets (tables) ----
#define OFF_POSQ  0        // [8*100] layout [h][l]
#define OFF_C0    800      // [8]
#define OFF_C1    808      // [8]
#define OFF_C2    816      // [8]
#define OFF_PV0   824      // [128]
#define OFF_PV1   952      // [128]
#define OFF_PVB   1080     // [128]
#define OFF_WC0   1208     // [128]
#define OFF_WC1   1336     // [128]
#define OFF_WCB   1464     // [128]
#define OFF_SB    1592     // [3]
#define OFF_PCB   1596     // [100]
#define OFF_PV    1696     // [100*128]  PV[l][hd]
#define OFF_PCT   14496    // [128*100]  PCt[hd][l]

__device__ __forceinline__ unsigned int umap(float v) {
  unsigned int b = __float_as_uint(v);
  return (b & 0x80000000u) ? ~b : (b | 0x80000000u);
}
__device__ __forceinline__ float unmap(unsigned int u) {
  unsigned int b = (u & 0x80000000u) ? (u ^ 0x80000000u) : ~u;
  return __uint_as_float(b);
}

// ---- fused precomp: block 0 = q-folded vectors; blocks 1..100 = per-l tables ----
__global__ __launch_bounds__(128) void precomp(
    const float* __restrict__ Wq, const float* __restrict__ Wk,
    const float* __restrict__ cur, const float* __restrict__ Wi,
    const float* __restrict__ bi, const float* __restrict__ Wv,
    const float* __restrict__ Wc, const float* __restrict__ bc,
    float* __restrict__ ws)
{
  const int tid = threadIdx.x;
  const int blk = blockIdx.x;
  __shared__ float pr[E_];
  __shared__ float red[8];
  const int lane = tid & 63, wvv = tid >> 6;

  if (blk == 0) {
    float qsv = 0.f;
    for (int e = 0; e < E_; ++e) qsv = fmaf(Wq[tid * E_ + e], cur[e], qsv);
    float wk0=0,wk1=0,wkb=0,pv0=0,pv1=0,pvb=0,wc0=0,wc1=0,wcb=0;
    for (int e = 0; e < E_; ++e) {
      float wi0 = Wi[2*e], wi1 = Wi[2*e+1], bie = bi[e];
      float wk = Wk[tid*E_+e], wvx = Wv[tid*E_+e], wcc = Wc[e*(H_*D_)+tid];
      wk0=fmaf(wk,wi0,wk0);  wk1=fmaf(wk,wi1,wk1);  wkb=fmaf(wk,bie,wkb);
      pv0=fmaf(wvx,wi0,pv0); pv1=fmaf(wvx,wi1,pv1); pvb=fmaf(wvx,bie,pvb);
      wc0=fmaf(wcc,wi0,wc0); wc1=fmaf(wcc,wi1,wc1); wcb=fmaf(wcc,bie,wcb);
    }
    ws[OFF_PV0+tid]=pv0; ws[OFF_PV1+tid]=pv1; ws[OFF_PVB+tid]=pvb;
    ws[OFF_WC0+tid]=wc0; ws[OFF_WC1+tid]=wc1; ws[OFF_WCB+tid]=wcb;
    float c0 = qsv*wk0, c1 = qsv*wk1, c2 = qsv*wkb;
    for (int off = 1; off < 16; off <<= 1) {
      c0 += __shfl_xor(c0, off, 16); c1 += __shfl_xor(c1, off, 16); c2 += __shfl_xor(c2, off, 16);
    }
    if ((tid & 15) == 0) {
      int h = tid >> 4;
      ws[OFF_C0+h] = c0*0.25f; ws[OFF_C1+h] = c1*0.25f; ws[OFF_C2+h] = c2*0.25f;
    }
    float p0 = Wi[2*tid]*bc[tid], p1 = Wi[2*tid+1]*bc[tid], p2 = bi[tid]*bc[tid];
    for (int off = 32; off > 0; off >>= 1) {
      p0 += __shfl_xor(p0, off, 64); p1 += __shfl_xor(p1, off, 64); p2 += __shfl_xor(p2, off, 64);
    }
    if (lane == 0) { red[wvv*3+0]=p0; red[wvv*3+1]=p1; red[wvv*3+2]=p2; }
    __syncthreads();
    if (tid == 0) {
      ws[OFF_SB+0]=red[0]+red[3]; ws[OFF_SB+1]=red[1]+red[4]; ws[OFF_SB+2]=red[2]+red[5];
    }
  } else {
    const int l = blk - 1;
    const float log_inc = 0.14619588050755848f;   // ln(10000)/63
    {
      int j = tid & 63;
      float scaled = (float)l * expf(-(float)j * log_inc);
      pr[tid] = (tid < 64) ? sinf(scaled) : cosf(scaled);
    }
    __syncthreads();
    float qsv=0.f, pwk=0.f, accv=0.f, accc=0.f;
    for (int e = 0; e < E_; ++e) qsv = fmaf(Wq[tid*E_+e], cur[e], qsv);
    for (int e = 0; e < E_; ++e) {
      float p = pr[e];
      pwk  = fmaf(Wk[tid*E_+e], p, pwk);
      accv = fmaf(Wv[tid*E_+e], p, accv);
      accc = fmaf(Wc[e*(H_*D_)+tid], p, accc);
    }
    ws[OFF_PV  + l*(H_*D_) + tid] = accv;
    ws[OFF_PCT + tid*L_ + l] = accc;
    float pq = qsv * pwk;
    for (int off = 1; off < 16; off <<= 1) pq += __shfl_xor(pq, off, 16);
    if ((tid & 15) == 0) ws[OFF_POSQ + (tid>>4)*L_ + l] = pq * 0.25f;
    float pb = pr[tid] * bc[tid];
    for (int off = 32; off > 0; off >>= 1) pb += __shfl_xor(pb, off, 64);
    if (lane == 0) red[wvv] = pb;
    __syncthreads();
    if (tid == 0) ws[OFF_PCB + l] = red[0] + red[1];
  }
}

// ==== K1: select top-100 per row -> state into out[0..483] ====
__global__ __launch_bounds__(128, 4) void k1_select(
    const float* __restrict__ dist, const float* __restrict__ theta,
    const float* __restrict__ ninf, float* __restrict__ out)
{
  __shared__ unsigned long long sel[CAP];   // 2 KB
  __shared__ unsigned int hist[256];        // fallback only
  __shared__ unsigned int wsum[2];
  __shared__ unsigned int s_cnt, s_chosen, s_cumb2;
  __shared__ float s_nrm;

  const int tid = threadIdx.x;
  const int lane = tid & 63, wv = tid >> 6;
  const size_t base = (size_t)blockIdx.x * N_;
  const float4* d4 = (const float4*)(dist + base);
  const float4* n4 = (const float4*)(ninf + base);

  sel[tid] = ~0ull; sel[tid + 128] = ~0ull;
  if (tid == 0) s_cnt = 0u;
  __syncthreads();

  // ---- single streaming pass: filter v < T0, push candidates ----
#pragma unroll 2
  for (int t = 0; t < 10; ++t) {
    int i4 = tid + 128 * t;
    if (i4 < NI4) {
      float4 dv = d4[i4], nv = n4[i4];
#pragma unroll
      for (int c = 0; c < 4; ++c) {
        float v = (&dv.x)[c] - (&nv.x)[c];
        if (v < T0) {
          unsigned int p = atomicAdd(&s_cnt, 1u);
          if (p < CAP) sel[p] = ((unsigned long long)umap(v) << 16) | (unsigned)(4 * i4 + c);
        }
      }
    }
  }
  __syncthreads();
  const unsigned int cnt = s_cnt;

  // ---- exact fallback (P ~ 1e-6/row on uniform data): 6x8-bit composite radix ----
  if (cnt < (unsigned)L_ || cnt > (unsigned)CAP) {
    unsigned long long prefix = 0ull;
    unsigned int Krem = L_;
    for (int pass = 0; pass < 6; ++pass) {
      const int shift = 40 - 8 * pass;
      hist[tid] = 0u; hist[tid + 128] = 0u;
      __syncthreads();
      for (int t = 0; t < 10; ++t) {
        int i4 = tid + 128 * t;
        if (i4 < NI4) {
          float4 dv = d4[i4], nv = n4[i4];
#pragma unroll
          for (int c = 0; c < 4; ++c) {
            float v = (&dv.x)[c] - (&nv.x)[c];
            unsigned long long key = ((unsigned long long)umap(v) << 16) | (unsigned)(4 * i4 + c);
            if ((key >> (shift + 8)) == prefix)
              atomicAdd(&hist[(unsigned)(key >> shift) & 0xFFu], 1u);
          }
        }
      }
      __syncthreads();
      unsigned int s0 = hist[2 * tid], s1 = hist[2 * tid + 1];
      unsigned int s = s0 + s1;
      unsigned int v = s;
#pragma unroll
      for (int off = 1; off < 64; off <<= 1) {
        unsigned int x = __shfl_up(v, off, 64);
        if (lane >= off) v += x;
      }
      if (lane == 63) wsum[wv] = v;
      __syncthreads();
      if (wv == 1) v += wsum[0];
      unsigned int cb = v - s;
      if (cb < Krem && v >= Krem) {
        if (cb + s0 >= Krem) { s_chosen = 2u * tid;     s_cumb2 = cb; }
        else                 { s_chosen = 2u * tid + 1; s_cumb2 = cb + s0; }
      }
      __syncthreads();
      prefix = (prefix << 8) | s_chosen;
      Krem -= s_cumb2;
      __syncthreads();
    }
    const unsigned long long kpiv = prefix;
    sel[tid] = ~0ull; sel[tid + 128] = ~0ull;
    if (tid == 0) s_cnt = 0u;
    __syncthreads();
    for (int t = 0; t < 10; ++t) {
      int i4 = tid + 128 * t;
      if (i4 < NI4) {
        float4 dv = d4[i4], nv = n4[i4];
#pragma unroll
        for (int c = 0; c < 4; ++c) {
          float v = (&dv.x)[c] - (&nv.x)[c];
          unsigned long long key = ((unsigned long long)umap(v) << 16) | (unsigned)(4 * i4 + c);
          if (key <= kpiv) {
            unsigned int p = atomicAdd(&s_cnt, 1u);
            if (p < CAP) sel[p] = key;   // exactly 100 distinct
          }
        }
      }
    }
    __syncthreads();
  }

  // ---- rank-by-count (distinct keys) + gathers hidden under rank loop ----
  {
    unsigned long long ka = sel[tid], kb = sel[tid + 128];
    const bool va = (ka != ~0ull), vb = (kb != ~0ull);
    unsigned int ixa = (unsigned int)(ka & 0xFFFFull);
    unsigned int ixb = (unsigned int)(kb & 0xFFFFull);
    float tha = 0.f, nma = 0.f, thb = 0.f, nmb = 0.f;
    if (va) { tha = theta[base + ixa]; nma = ninf[base + ixa]; }
    if (vb) { thb = theta[base + ixb]; nmb = ninf[base + ixb]; }
    int ra = 0, rb = 0;
#pragma unroll 8
    for (int j = 0; j < CAP; ++j) {
      unsigned long long kj = sel[j];
      ra += (kj < ka) ? 1 : 0;
      rb += (kj < kb) ? 1 : 0;
    }
    float sda = unmap((unsigned int)(ka >> 16));
    float sdb = unmap((unsigned int)(kb >> 16));
    if (va && ra == 99) s_nrm = sda;
    if (vb && rb == 99) s_nrm = sdb;
    __syncthreads();
    const float invn = 1.0f / (s_nrm + 1e-6f);
    if (va && ra < L_) {
      out[base + ST_SD + ra] = sda * invn;
      out[base + ST_TH + ra] = tha;
      out[base + ST_SM + ra] = nma;
      out[base + ST_IX + ra] = __uint_as_float(ixa);
    }
    if (vb && rb < L_) {
      out[base + ST_SD + rb] = sdb * invn;
      out[base + ST_TH + rb] = thb;
      out[base + ST_SM + rb] = nmb;
      out[base + ST_IX + rb] = __uint_as_float(ixb);
    }
  }
}

// ==== K2: attention math per row: state -> s2 into out[512..611] ====
__global__ __launch_bounds__(128, 4) void k2_math(
    const float* __restrict__ ws, float* __restrict__ out)
{
  __shared__ float sdv[128], stv[128], smv[128];
  __shared__ float att[H_ * D_];

  const int tid = threadIdx.x;
  const size_t base = (size_t)blockIdx.x * N_;

  if (tid < L_) {
    sdv[tid] = out[base + ST_SD + tid];
    stv[tid] = out[base + ST_TH + tid];
    smv[tid] = out[base + ST_SM + tid];
  }
  __syncthreads();

  // score + softmax + att: 16 lanes per head over 128 threads
  {
    const int hh = tid >> 4, jj = tid & 15;
    float w7[7];
    float a0, a1;
    const float c0 = ws[OFF_C0 + hh], c1 = ws[OFF_C1 + hh], c2 = ws[OFF_C2 + hh];
    float mx = -INFINITY;
#pragma unroll
    for (int k = 0; k < 7; ++k) {
      int l = jj + 16 * k;
      float scv = -INFINITY;
      if (l < L_)
        scv = fmaf(sdv[l], c0, fmaf(stv[l], c1, c2 + ws[OFF_POSQ + hh * L_ + l] + smv[l]));
      w7[k] = scv;
      mx = fmaxf(mx, scv);
    }
#pragma unroll
    for (int off = 1; off <= 8; off <<= 1) mx = fmaxf(mx, __shfl_xor(mx, off, 64));
    float sum = 0.f;
#pragma unroll
    for (int k = 0; k < 7; ++k) { float e = expf(w7[k] - mx); w7[k] = e; sum += e; }
#pragma unroll
    for (int off = 1; off <= 8; off <<= 1) sum += __shfl_xor(sum, off, 64);
    const float inv = 1.0f / sum;
    a0 = 0.f; a1 = 0.f;
#pragma unroll
    for (int k = 0; k < 7; ++k) {
      int l = jj + 16 * k; int lc = (l < L_) ? l : 0;
      float wgt = w7[k] * inv; w7[k] = wgt;
      a0 = fmaf(wgt, sdv[lc], a0);
      a1 = fmaf(wgt, stv[lc], a1);
    }
#pragma unroll
    for (int off = 1; off <= 8; off <<= 1) { a0 += __shfl_xor(a0, off, 64); a1 += __shfl_xor(a1, off, 64); }
    {
      float part[16];
#pragma unroll
      for (int t = 0; t < 16; ++t) part[t] = 0.f;
#pragma unroll
      for (int k = 0; k < 7; ++k) {
        int l = jj + 16 * k;
        if (l < L_) {
          const float* pv = ws + OFF_PV + l * (H_ * D_) + hh * 16;
          float wgt = w7[k];
#pragma unroll
          for (int t = 0; t < 16; ++t) part[t] = fmaf(wgt, pv[t], part[t]);
        }
      }
#pragma unroll
      for (int off = 1; off <= 8; off <<= 1) {
#pragma unroll
        for (int t = 0; t < 16; ++t) part[t] += __shfl_xor(part[t], off, 64);
      }
#pragma unroll
      for (int t = 0; t < 16; ++t) {   // 16 lanes write identical value
        int hd = hh * 16 + t;
        att[hd] = fmaf(a0, ws[OFF_PV0 + hd], fmaf(a1, ws[OFF_PV1 + hd], ws[OFF_PVB + hd])) + part[t];
      }
    }
  }
  __syncthreads();

  // m0/m1/mb: 64-wide reduce over att (both waves redundant)
  float m0, m1, mb;
  {
    const int lane = tid & 63;
    float x0 = att[lane], x1 = att[lane + 64];
    m0 = fmaf(x0, ws[OFF_WC0 + lane], x1 * ws[OFF_WC0 + lane + 64]);
    m1 = fmaf(x0, ws[OFF_WC1 + lane], x1 * ws[OFF_WC1 + lane + 64]);
    mb = fmaf(x0, ws[OFF_WCB + lane], x1 * ws[OFF_WCB + lane + 64]);
#pragma unroll
    for (int off = 1; off < 64; off <<= 1) {
      m0 += __shfl_xor(m0, off, 64);
      m1 += __shfl_xor(m1, off, 64);
      mb += __shfl_xor(mb, off, 64);
    }
    m0 += ws[OFF_SB + 0]; m1 += ws[OFF_SB + 1]; mb += ws[OFF_SB + 2];
  }

  // s2[l]
  if (tid < L_) {
    float acc = ws[OFF_PCB + tid];
#pragma unroll 16
    for (int hd = 0; hd < H_ * D_; ++hd) acc = fmaf(att[hd], ws[OFF_PCT + hd * L_ + tid], acc);
    const float SC = 0.08838834764831845f;   // 1/sqrt(E)
    out[base + ST_S2 + tid] = (fmaf(sdv[tid], m0, fmaf(stv[tid], m1, mb)) + acc) * SC;
  }
}

// ==== K3: zero + scatter, fused coalesced write ====
__global__ __launch_bounds__(256, 4) void k3_write(float* __restrict__ out)
{
  __shared__ unsigned int bitmap[160];
  __shared__ unsigned int hidx[256];
  __shared__ float hval[256];

  const int tid = threadIdx.x;
  const size_t base = (size_t)blockIdx.x * N_;

  // read state BEFORE overwriting the row
  unsigned int myidx = 0u; float myval = 0.f;
  if (tid < L_) {
    myidx = __float_as_uint(out[base + ST_IX + tid]);
    myval = out[base + ST_S2 + tid];
  }
  hidx[tid] = 0xFFFFFFFFu;
  if (tid < 160) bitmap[tid] = 0u;
  __syncthreads();
  if (tid < L_) {
    unsigned int p = myidx & 255u;
    while (atomicCAS(&hidx[p], 0xFFFFFFFFu, myidx) != 0xFFFFFFFFu) p = (p + 1) & 255u;
    hval[p] = myval;
    atomicOr(&bitmap[myidx >> 5], 1u << (myidx & 31));
  }
  __syncthreads();

  float4* o4 = (float4*)(out + base);
#pragma unroll
  for (int t = 0; t < 5; ++t) {
    int i4 = tid + 256 * t;
    if (i4 < NI4) {
      unsigned int wbits = (bitmap[i4 >> 3] >> ((i4 & 7) * 4)) & 0xFu;
      float4 o = make_float4(0.f, 0.f, 0.f, 0.f);
      if (wbits) {
#pragma unroll
        for (int c = 0; c < 4; ++c) {
          if ((wbits >> c) & 1u) {
            unsigned int idx = (unsigned int)(4 * i4 + c);
            unsigned int p = idx & 255u;
            while (hidx[p] != idx) p = (p + 1) & 255u;
            (&o.x)[c] = hval[p];
          }
        }
      }
      o4[i4] = o;
    }
  }
}

extern "C" void kernel_launch(void* const* d_in, const int* in_sizes, int n_in,
                              void* d_out, int out_size, void* d_ws, size_t ws_size,
                              hipStream_t stream) {
  const float* dist = (const float*)d_in[0];
  const float* theta = (const float*)d_in[1];
  const float* ninf = (const float*)d_in[2];
  const float* Wi   = (const float*)d_in[3];
  const float* bi   = (const float*)d_in[4];
  const float* cur  = (const float*)d_in[5];
  const float* Wq   = (const float*)d_in[6];
  const float* Wk   = (const float*)d_in[7];
  const float* Wv   = (const float*)d_in[8];
  const float* Wc   = (const float*)d_in[9];
  const float* bcv  = (const float*)d_in[10];
  float* out = (float*)d_out;
  float* ws  = (float*)d_ws;

  precomp<<<dim3(L_ + 1), dim3(128), 0, stream>>>(Wq, Wk, cur, Wi, bi, Wv, Wc, bcv, ws);
  k1_select<<<dim3(B_ * M_), dim3(128), 0, stream>>>(dist, theta, ninf, out);
  k2_math<<<dim3(B_ * M_), dim3(128), 0, stream>>>(ws, out);
  k3_write<<<dim3(B_ * M_), dim3(256), 0, stream>>>(out);
}